// Round 7
// baseline (203.060 us; speedup 1.0000x reference)
//
#include <hip/hip_runtime.h>
#include <hip/hip_bf16.h>

typedef __bf16 bf16_t;
typedef __bf16 bf16x8 __attribute__((ext_vector_type(8)));
typedef __bf16 bf16x4 __attribute__((ext_vector_type(4)));
typedef float  f32x4  __attribute__((ext_vector_type(4)));

#define NB  8
#define NC  256
#define NC8 32
#define NN  4096
#define XS  264   // xs row stride in xpose (528B = 33*16, b128-aligned)

#define MFMA16(a, b, c) __builtin_amdgcn_mfma_f32_16x16x32_bf16((a), (b), (c), 0, 0, 0)

// ---------------------------------------------------------------------------
// Kernel 0: fp32 -> bf16 for all three weight matrices in one launch.
// ---------------------------------------------------------------------------
__global__ __launch_bounds__(256) void cvt_all(const float* __restrict__ wq,
                                               const float* __restrict__ wk,
                                               const float* __restrict__ wv,
                                               bf16_t* __restrict__ wqb,
                                               bf16_t* __restrict__ wkb,
                                               bf16_t* __restrict__ wvb) {
    int i = blockIdx.x * 256 + threadIdx.x;   // 0..20479
    const float* src; bf16_t* dst; int off;
    if (i < 2048)      { src = wq; dst = wqb; off = i; }
    else if (i < 4096) { src = wk; dst = wkb; off = i - 2048; }
    else               { src = wv; dst = wvb; off = i - 4096; }
    float4 v = reinterpret_cast<const float4*>(src)[off];
    bf16x4 o;
    o[0] = (bf16_t)v.x; o[1] = (bf16_t)v.y; o[2] = (bf16_t)v.z; o[3] = (bf16_t)v.w;
    reinterpret_cast<bf16x4*>(dst)[off] = o;
}

// ---------------------------------------------------------------------------
// Kernel 1a: transpose + cvt: x[b][c][n] fp32 -> xT[b][n][c] bf16 (in d_out
// scratch). Pure memory kernel; the proven two-phase LDS transpose from the
// old proj_fused, then 4KB-contiguous stores. No weights, no MFMA.
// ---------------------------------------------------------------------------
__global__ __launch_bounds__(256) void xpose(const float* __restrict__ x,
                                             bf16_t* __restrict__ xt) {
    __shared__ bf16_t tile[64][72];
    __shared__ bf16_t xs[64 * XS];      // [n_loc][c]

    const int bx = blockIdx.x;          // 512
    const int b  = bx >> 6;
    const int n0 = (bx & 63) * 64;
    const int t  = threadIdx.x;

    const int cl  = t >> 4;
    const int nl  = (t & 15) * 4;
    const int nb_ = t >> 3;
    const int cl2 = (t & 7) * 8;

    // ---- hoisted x loads: all 16 in flight at once
    float4 xv[16];
#pragma unroll
    for (int cp = 0; cp < 4; ++cp)
#pragma unroll
        for (int p = 0; p < 4; ++p)
            xv[4 * cp + p] = *reinterpret_cast<const float4*>(
                x + ((size_t)b * NC + 64 * cp + cl + 16 * p) * NN + n0 + nl);

    for (int cp = 0; cp < 4; ++cp) {
#pragma unroll
        for (int p = 0; p < 4; ++p) {
            const int cc = cl + 16 * p;
            float4 v = xv[4 * cp + p];
            bf16x4 bv4;
            bv4[0] = (bf16_t)v.x; bv4[1] = (bf16_t)v.y; bv4[2] = (bf16_t)v.z; bv4[3] = (bf16_t)v.w;
            *reinterpret_cast<bf16x4*>(&tile[cc][nl]) = bv4;
        }
        __syncthreads();
#pragma unroll
        for (int p = 0; p < 2; ++p) {
            const int nn = nb_ + 32 * p;
            bf16x8 v;
            for (int i = 0; i < 8; ++i) v[i] = tile[cl2 + i][nn];
            *reinterpret_cast<bf16x8*>(&xs[nn * XS + 64 * cp + cl2]) = v;
        }
        __syncthreads();
    }

    // ---- store xs -> xT[b][n0+rr][c]; each instr: 8 rows x 512B contiguous
    const int row = t >> 5;        // 0..7
    const int ch  = t & 31;        // c-chunk of 8 bf16 (16B)
#pragma unroll
    for (int p = 0; p < 8; ++p) {
        const int rr = row + 8 * p;
        bf16x8 v = *reinterpret_cast<const bf16x8*>(&xs[rr * XS + ch * 8]);
        *reinterpret_cast<bf16x8*>(xt + ((size_t)b * NN + n0 + rr) * NC + ch * 8) = v;
    }
}

// ---------------------------------------------------------------------------
// Kernel 1b: projections as barrier-free, LDS-free per-wave GEMMs on xT.
// A/B fragments load straight from xT (coalesced 64B-segment reads) and the
// bf16 weights; depth-1 prefetch on both. Waves fully independent.
// ---------------------------------------------------------------------------
__global__ __launch_bounds__(256) void projmm(const bf16_t* __restrict__ xt,
                                              const bf16_t* __restrict__ wq,
                                              const float* __restrict__ bq,
                                              const bf16_t* __restrict__ wk,
                                              const float* __restrict__ bk,
                                              const bf16_t* __restrict__ wv,
                                              const float* __restrict__ bv,
                                              bf16_t* __restrict__ ft,
                                              bf16_t* __restrict__ gt,
                                              bf16_t* __restrict__ h) {
    const int bx = blockIdx.x;          // 512
    const int b  = bx >> 6;
    const int n0 = (bx & 63) * 64;
    const int t  = threadIdx.x;
    const int w    = t >> 6;
    const int lane = t & 63;
    const int q    = lane >> 4;
    const int r    = lane & 15;

    const bf16_t* xb = xt + ((size_t)b * NN + n0) * NC;   // [64][256] tile

    // ---- q/k projections: wave w owns n-rows 16w..16w+15
    {
        const bf16_t* xrow = xb + (size_t)(16 * w + r) * NC;
        f32x4 accq[2], acck[2];
        for (int ot = 0; ot < 2; ++ot) {
            accq[ot] = (f32x4){0.f, 0.f, 0.f, 0.f};
            acck[ot] = (f32x4){0.f, 0.f, 0.f, 0.f};
        }
        bf16x8 a_c  = *reinterpret_cast<const bf16x8*>(xrow + 8 * q);
        bf16x8 fq_c[2], fk_c[2];
#pragma unroll
        for (int ot = 0; ot < 2; ++ot) {
            fq_c[ot] = *reinterpret_cast<const bf16x8*>(wq + (size_t)(16 * ot + r) * NC + 8 * q);
            fk_c[ot] = *reinterpret_cast<const bf16x8*>(wk + (size_t)(16 * ot + r) * NC + 8 * q);
        }
        for (int k0 = 0; k0 < NC; k0 += 32) {
            const int kn = (k0 + 32 < NC) ? k0 + 32 : 0;
            bf16x8 a_n = *reinterpret_cast<const bf16x8*>(xrow + kn + 8 * q);
            bf16x8 fq_n[2], fk_n[2];
#pragma unroll
            for (int ot = 0; ot < 2; ++ot) {
                fq_n[ot] = *reinterpret_cast<const bf16x8*>(wq + (size_t)(16 * ot + r) * NC + kn + 8 * q);
                fk_n[ot] = *reinterpret_cast<const bf16x8*>(wk + (size_t)(16 * ot + r) * NC + kn + 8 * q);
            }
#pragma unroll
            for (int ot = 0; ot < 2; ++ot) {
                accq[ot] = MFMA16(a_c, fq_c[ot], accq[ot]);
                acck[ot] = MFMA16(a_c, fk_c[ot], acck[ot]);
            }
            a_c = a_n;
#pragma unroll
            for (int ot = 0; ot < 2; ++ot) { fq_c[ot] = fq_n[ot]; fk_c[ot] = fk_n[ot]; }
        }
        for (int ot = 0; ot < 2; ++ot) {
            const int o = 16 * ot + r;
            const float biq = bq[o];
            const float bik = bk[o];
            for (int i = 0; i < 4; ++i) {
                const int n = n0 + 16 * w + 4 * q + i;
                ft[((size_t)b * NN + n) * NC8 + o] = (bf16_t)(accq[ot][i] + biq);
                gt[((size_t)b * NN + n) * NC8 + o] = (bf16_t)(acck[ot][i] + bik);
            }
        }
    }

    // ---- v projection: wave w owns c-rows 64w..64w+63; all 64 n
    f32x4 vacc[4][4];
    for (int ct = 0; ct < 4; ++ct)
        for (int nt = 0; nt < 4; ++nt) vacc[ct][nt] = (f32x4){0.f, 0.f, 0.f, 0.f};

    bf16x8 wv_c[4], bfr_c[4];
#pragma unroll
    for (int ct = 0; ct < 4; ++ct)
        wv_c[ct] = *reinterpret_cast<const bf16x8*>(
            wv + (size_t)(64 * ct + 16 * w + r) * NC + 8 * q);
#pragma unroll
    for (int nt = 0; nt < 4; ++nt)
        bfr_c[nt] = *reinterpret_cast<const bf16x8*>(xb + (size_t)(16 * nt + r) * NC + 8 * q);

    for (int k0 = 0; k0 < NC; k0 += 32) {
        const int kn = (k0 + 32 < NC) ? k0 + 32 : 0;
        bf16x8 wv_n[4], bfr_n[4];
#pragma unroll
        for (int ct = 0; ct < 4; ++ct)
            wv_n[ct] = *reinterpret_cast<const bf16x8*>(
                wv + (size_t)(64 * ct + 16 * w + r) * NC + kn + 8 * q);
#pragma unroll
        for (int nt = 0; nt < 4; ++nt)
            bfr_n[nt] = *reinterpret_cast<const bf16x8*>(xb + (size_t)(16 * nt + r) * NC + kn + 8 * q);
#pragma unroll
        for (int ct = 0; ct < 4; ++ct)
#pragma unroll
            for (int nt = 0; nt < 4; ++nt)
                vacc[ct][nt] = MFMA16(wv_c[ct], bfr_c[nt], vacc[ct][nt]);
#pragma unroll
        for (int ct = 0; ct < 4; ++ct) wv_c[ct] = wv_n[ct];
#pragma unroll
        for (int nt = 0; nt < 4; ++nt) bfr_c[nt] = bfr_n[nt];
    }
    // ---- h epilogue: tiled layout h32[b][n/32][c][n%32]
    for (int ct = 0; ct < 4; ++ct) {
        for (int nt = 0; nt < 4; ++nt) {
            const int n32 = (n0 >> 5) + (nt >> 1);          // global n/32 chunk
            const int dn  = 16 * (nt & 1) + r;              // n%32
            for (int i = 0; i < 4; ++i) {
                const int c = 64 * ct + 16 * w + 4 * q + i;
                h[(((size_t)b * 128 + n32) * NC + c) * 32 + dn] = (bf16_t)(vacc[ct][nt][i] + bv[c]);
            }
        }
    }
}

// ---------------------------------------------------------------------------
// Kernel 2: attention, 8 waves / BN=128, non-draining barrier, tiled h32
// layout (byte-identical to round 6: 90.8 us, MfmaUtil 36.5).
// ---------------------------------------------------------------------------
#define O_STEP(HU, HL, KC, LOFF)                                               \
    {                                                                          \
        _Pragma("unroll")                                                      \
        for (int ct = 0; ct < 2; ++ct)                                         \
            HL[ct] = *reinterpret_cast<const bf16x8*>(                         \
                hrow[ct] + (size_t)(LOFF) * 256);                              \
        bf16x8 pf[4];                                                          \
        _Pragma("unroll")                                                      \
        for (int mt = 0; mt < 4; ++mt) {                                       \
            const int row = 16 * mt + r;                                       \
            pf[mt] = *reinterpret_cast<const bf16x8*>(                         \
                &Pb[(row << 7) + (((4 * (KC) + q) ^ rq) << 3)]);               \
        }                                                                      \
        _Pragma("unroll")                                                      \
        for (int ct = 0; ct < 2; ++ct)                                         \
            _Pragma("unroll")                                                  \
            for (int mt = 0; mt < 4; ++mt)                                     \
                acc[ct][mt] = MFMA16(HU[ct], pf[mt], acc[ct][mt]);             \
    }

__global__ __launch_bounds__(512, 4) void attn(const bf16_t* __restrict__ ft,
                                               const bf16_t* __restrict__ gt,
                                               const bf16_t* __restrict__ h,
                                               float* __restrict__ out) {
    __shared__ bf16_t P[2 * 64 * 128];   // 32 KB, double buffered
    __shared__ float  l_lds[64];

    const int bx = blockIdx.x;       // 512
    const int b  = bx & 7;           // XCD pin
    const int m0 = (bx >> 3) * 64;
    const int tid  = threadIdx.x;
    const int w    = tid >> 6;       // 0..7
    const int lane = tid & 63;
    const int q    = lane >> 4;
    const int r    = lane & 15;
    const int rq   = r & 7;

    if (tid < 64) l_lds[tid] = 0.f;

    bf16x8 qf[4];
#pragma unroll
    for (int mt = 0; mt < 4; ++mt)
        qf[mt] = *reinterpret_cast<const bf16x8*>(
            gt + ((size_t)b * NN + m0 + 16 * mt + r) * NC8 + 8 * q);

    f32x4 acc[2][4];
#pragma unroll
    for (int ct = 0; ct < 2; ++ct)
#pragma unroll
        for (int mt = 0; mt < 4; ++mt) acc[ct][mt] = (f32x4){0.f, 0.f, 0.f, 0.f};
    float lp[4] = {0.f, 0.f, 0.f, 0.f};

    const bf16_t* fb = ft + (size_t)b * NN * NC8;
    const bf16_t* hb = h + (size_t)b * 128 * NC * 32;   // h32[b]...
    const f32x4 zero = (f32x4){0.f, 0.f, 0.f, 0.f};

    const bf16_t* hrow[2];
#pragma unroll
    for (int ct = 0; ct < 2; ++ct)
        hrow[ct] = hb + (size_t)(32 * w + 16 * ct + r) * 32 + 8 * q;
    const bf16_t* fptr = fb + (size_t)(16 * w + r) * NC8 + 8 * q;

    // ---- prologue: s(chunk 0); h0 = chunk0/kc0
    f32x4 s[4];
    {
        bf16x8 a0 = *reinterpret_cast<const bf16x8*>(fptr);
#pragma unroll
        for (int mt = 0; mt < 4; ++mt) s[mt] = MFMA16(a0, qf[mt], zero);
    }
    bf16x8 h0[2], h1[2];
#pragma unroll
    for (int ct = 0; ct < 2; ++ct)
        h0[ct] = *reinterpret_cast<const bf16x8*>(hrow[ct]);

    for (int ii = 0; ii < 32; ++ii) {
        bf16_t* Pb = &P[(ii & 1) << 13];
        const int nb = ii * 128;
        const int nld = (ii + 1 < 32 ? ii + 1 : 31) * 128;

        // ---- issue af load for chunk ii+1 FIRST (max slack, crosses barrier)
        bf16x8 af0 = *reinterpret_cast<const bf16x8*>(fptr + (size_t)nld * NC8);

        // ---- exp + write P[cur]
#pragma unroll
        for (int mt = 0; mt < 4; ++mt) {
            float e0 = __expf(s[mt][0]);
            float e1 = __expf(s[mt][1]);
            float e2 = __expf(s[mt][2]);
            float e3 = __expf(s[mt][3]);
            lp[mt] += (e0 + e1) + (e2 + e3);
            bf16x4 pv;
            pv[0] = (bf16_t)e0; pv[1] = (bf16_t)e1; pv[2] = (bf16_t)e2; pv[3] = (bf16_t)e3;
            const int row  = 16 * mt + r;
            const int nblk = 2 * w + (q >> 1);
            *reinterpret_cast<bf16x4*>(
                &Pb[(row << 7) + ((nblk ^ rq) << 3) + 4 * (q & 1)]) = pv;
        }

        // ---- NON-DRAINING barrier: order LDS only; VMEM prefetch survives
        asm volatile("s_waitcnt lgkmcnt(0)" ::: "memory");
        __builtin_amdgcn_sched_barrier(0);
        __builtin_amdgcn_s_barrier();
        __builtin_amdgcn_sched_barrier(0);

        // ---- O phase: 4 k-chunks of 32 n, h ping-pong one chunk ahead
        const int nbn = (ii + 1 < 32 ? nb + 128 : nb);
        __builtin_amdgcn_s_setprio(1);
        O_STEP(h0, h1, 0, nb + 32);
        O_STEP(h1, h0, 1, nb + 64);
        O_STEP(h0, h1, 2, nb + 96);
        O_STEP(h1, h0, 3, nbn);

        // ---- S(ii+1)
#pragma unroll
        for (int mt = 0; mt < 4; ++mt) s[mt] = MFMA16(af0, qf[mt], zero);
        __builtin_amdgcn_s_setprio(0);
    }

    // ---- reduce l partials
    __syncthreads();
#pragma unroll
    for (int mt = 0; mt < 4; ++mt) {
        float v = lp[mt];
        v += __shfl_xor(v, 16);
        v += __shfl_xor(v, 32);
        if (q == 0) atomicAdd(&l_lds[16 * mt + r], v);
    }
    __syncthreads();

    // ---- epilogue: out[b][c][m] = acc / l[m]
#pragma unroll
    for (int ct = 0; ct < 2; ++ct) {
#pragma unroll
        for (int mt = 0; mt < 4; ++mt) {
            const int m = m0 + 16 * mt + r;
            const float linv = 1.0f / l_lds[16 * mt + r];
#pragma unroll
            for (int i = 0; i < 4; ++i) {
                const int c = 32 * w + 16 * ct + 4 * q + i;
                out[((size_t)b * NC + c) * NN + m] = acc[ct][mt][i] * linv;
            }
        }
    }
}

extern "C" void kernel_launch(void* const* d_in, const int* in_sizes, int n_in,
                              void* d_out, int out_size, void* d_ws, size_t ws_size,
                              hipStream_t stream) {
    const float* x  = (const float*)d_in[0];
    const float* wq = (const float*)d_in[1];
    const float* bq = (const float*)d_in[2];
    const float* wk = (const float*)d_in[3];
    const float* bk = (const float*)d_in[4];
    const float* wv = (const float*)d_in[5];
    const float* bv = (const float*)d_in[6];
    float* out = (float*)d_out;

    bf16_t* ft  = (bf16_t*)d_ws;                     // [B][N][32]
    bf16_t* gt  = ft + (size_t)NB * NN * NC8;        // [B][N][32]
    bf16_t* hb  = gt + (size_t)NB * NN * NC8;        // h32: [B][N/32][C][32]
    bf16_t* wqb = hb + (size_t)NB * NC * NN;         // [32][256]
    bf16_t* wkb = wqb + (size_t)NC8 * NC;            // [32][256]
    bf16_t* wvb = wkb + (size_t)NC8 * NC;            // [256][256]

    // xT scratch lives in d_out (16.8 MB of 33.5 MB); attn overwrites out
    // completely afterwards (stream-ordered), so no conflict.
    bf16_t* xT = (bf16_t*)out;                       // [B][N][C] bf16

    cvt_all<<<80, 256, 0, stream>>>(wq, wk, wv, wqb, wkb, wvb);
    xpose<<<NB * (NN / 64), 256, 0, stream>>>(x, xT);
    projmm<<<NB * (NN / 64), 256, 0, stream>>>(xT, wqb, bq, wkb, bk, wvb, bv, ft, gt, hb);
    attn<<<NB * (NN / 64), 512, 0, stream>>>(ft, gt, hb, out);
}

// Round 8
// 196.045 us; speedup vs baseline: 1.0358x; 1.0358x over previous
//
#include <hip/hip_runtime.h>
#include <hip/hip_bf16.h>

typedef __bf16 bf16_t;
typedef __bf16 bf16x8 __attribute__((ext_vector_type(8)));
typedef __bf16 bf16x4 __attribute__((ext_vector_type(4)));
typedef float  f32x4  __attribute__((ext_vector_type(4)));

#define NB  8
#define NC  256
#define NC8 32
#define NN  4096
#define XS  264   // xs row stride in xpose (528B = 33*16, b128-aligned)

#define MFMA16(a, b, c) __builtin_amdgcn_mfma_f32_16x16x32_bf16((a), (b), (c), 0, 0, 0)

// ---------------------------------------------------------------------------
// Panel layout (all MFMA fragment sources):
//   mat[R][256] -> panels[(o/16)*8 + k/32][16][32], element (o,k) at
//   panel*512 + (o&15)*32 + (k&31).  One fragment load per wave =
//   panel + r*32 + 8q  -> fully contiguous 1KB (no row scatter).
// ---------------------------------------------------------------------------

// ---------------------------------------------------------------------------
// Kernel 0: fp32 -> bf16 + PANELIZE all three weight matrices.
// ---------------------------------------------------------------------------
__global__ __launch_bounds__(256) void cvt_all(const float* __restrict__ wq,
                                               const float* __restrict__ wk,
                                               const float* __restrict__ wv,
                                               bf16_t* __restrict__ wqb,
                                               bf16_t* __restrict__ wkb,
                                               bf16_t* __restrict__ wvb) {
    int i = blockIdx.x * 256 + threadIdx.x;   // 0..20479
    const float* src; bf16_t* dst; int off;
    if (i < 2048)      { src = wq; dst = wqb; off = i; }
    else if (i < 4096) { src = wk; dst = wkb; off = i - 2048; }
    else               { src = wv; dst = wvb; off = i - 4096; }
    float4 v = reinterpret_cast<const float4*>(src)[off];
    const int e = off * 4;        // element offset in row-major [R][256]
    const int o = e >> 8;         // row
    const int k = e & 255;        // col (multiple of 4 -> stays in one panel)
    const size_t d = (size_t)((o >> 4) * 8 + (k >> 5)) * 512 + (o & 15) * 32 + (k & 31);
    bf16x4 ov;
    ov[0] = (bf16_t)v.x; ov[1] = (bf16_t)v.y; ov[2] = (bf16_t)v.z; ov[3] = (bf16_t)v.w;
    *reinterpret_cast<bf16x4*>(dst + d) = ov;
}

// ---------------------------------------------------------------------------
// Kernel 1a: transpose + cvt: x[b][c][n] fp32 -> xP panels (in d_out scratch)
//   xP[b][n/16][k/32][16][32]; per-thread 16B chunks land contiguous,
//   4-lane groups form 64B segments.
// ---------------------------------------------------------------------------
__global__ __launch_bounds__(256) void xpose(const float* __restrict__ x,
                                             bf16_t* __restrict__ xt) {
    __shared__ bf16_t tile[64][72];
    __shared__ bf16_t xs[64 * XS];      // [n_loc][c]

    const int bx = blockIdx.x;          // 512
    const int b  = bx >> 6;
    const int n0 = (bx & 63) * 64;
    const int t  = threadIdx.x;

    const int cl  = t >> 4;
    const int nl  = (t & 15) * 4;
    const int nb_ = t >> 3;
    const int cl2 = (t & 7) * 8;

    // ---- hoisted x loads: all 16 in flight at once
    float4 xv[16];
#pragma unroll
    for (int cp = 0; cp < 4; ++cp)
#pragma unroll
        for (int p = 0; p < 4; ++p)
            xv[4 * cp + p] = *reinterpret_cast<const float4*>(
                x + ((size_t)b * NC + 64 * cp + cl + 16 * p) * NN + n0 + nl);

    for (int cp = 0; cp < 4; ++cp) {
#pragma unroll
        for (int p = 0; p < 4; ++p) {
            const int cc = cl + 16 * p;
            float4 v = xv[4 * cp + p];
            bf16x4 bv4;
            bv4[0] = (bf16_t)v.x; bv4[1] = (bf16_t)v.y; bv4[2] = (bf16_t)v.z; bv4[3] = (bf16_t)v.w;
            *reinterpret_cast<bf16x4*>(&tile[cc][nl]) = bv4;
        }
        __syncthreads();
#pragma unroll
        for (int p = 0; p < 2; ++p) {
            const int nn = nb_ + 32 * p;
            bf16x8 v;
            for (int i = 0; i < 8; ++i) v[i] = tile[cl2 + i][nn];
            *reinterpret_cast<bf16x8*>(&xs[nn * XS + 64 * cp + cl2]) = v;
        }
        __syncthreads();
    }

    // ---- store xs -> panels
    const int row = t >> 5;        // 0..7
    const int ch  = t & 31;        // c-chunk of 8 bf16
    const int kp  = ch >> 2;       // k/32
    const int c8  = (ch & 3) * 8;  // k%32
#pragma unroll
    for (int p = 0; p < 8; ++p) {
        const int rr = row + 8 * p;                       // n within 64-tile
        bf16x8 v = *reinterpret_cast<const bf16x8*>(&xs[rr * XS + ch * 8]);
        const int np = (n0 >> 4) + (rr >> 4);             // global n/16
        *reinterpret_cast<bf16x8*>(
            xt + ((size_t)(b * 256 + np) * 8 + kp) * 512 + (rr & 15) * 32 + c8) = v;
    }
}

// ---------------------------------------------------------------------------
// Kernel 1b: projections; barrier-free, LDS-free per-wave GEMMs.
// ALL fragment loads (activations via xP, weights via panelized w*) are
// contiguous 1KB wave reads. Depth-1 prefetch on everything.
// ---------------------------------------------------------------------------
__global__ __launch_bounds__(256) void projmm(const bf16_t* __restrict__ xt,
                                              const bf16_t* __restrict__ wq,
                                              const float* __restrict__ bq,
                                              const bf16_t* __restrict__ wk,
                                              const float* __restrict__ bk,
                                              const bf16_t* __restrict__ wv,
                                              const float* __restrict__ bv,
                                              bf16_t* __restrict__ ft,
                                              bf16_t* __restrict__ gt,
                                              bf16_t* __restrict__ h) {
    const int bx = blockIdx.x;          // 512
    const int b  = bx >> 6;
    const int n0 = (bx & 63) * 64;
    const int t  = threadIdx.x;
    const int w    = t >> 6;
    const int lane = t & 63;
    const int q    = lane >> 4;
    const int r    = lane & 15;

    const int fo = r * 32 + 8 * q;                        // within-panel frag offset
    const bf16_t* xpb = xt + (size_t)b * 256 * 8 * 512;   // b panel base

    // ---- q/k projections: wave w owns n-rows [16w,16w+16) of the 64-tile
    {
        const bf16_t* apan = xpb + (size_t)((n0 >> 4) + w) * 4096 + fo;  // + kp*512
        const bf16_t* wqp  = wq + fo;                                    // + ot*4096 + kp*512
        const bf16_t* wkp  = wk + fo;
        f32x4 accq[2], acck[2];
        for (int ot = 0; ot < 2; ++ot) {
            accq[ot] = (f32x4){0.f, 0.f, 0.f, 0.f};
            acck[ot] = (f32x4){0.f, 0.f, 0.f, 0.f};
        }
        bf16x8 a_c = *reinterpret_cast<const bf16x8*>(apan);
        bf16x8 fq_c[2], fk_c[2];
#pragma unroll
        for (int ot = 0; ot < 2; ++ot) {
            fq_c[ot] = *reinterpret_cast<const bf16x8*>(wqp + ot * 4096);
            fk_c[ot] = *reinterpret_cast<const bf16x8*>(wkp + ot * 4096);
        }
        for (int kp = 0; kp < 8; ++kp) {
            const int kn = (kp + 1 < 8) ? kp + 1 : 0;
            bf16x8 a_n = *reinterpret_cast<const bf16x8*>(apan + kn * 512);
            bf16x8 fq_n[2], fk_n[2];
#pragma unroll
            for (int ot = 0; ot < 2; ++ot) {
                fq_n[ot] = *reinterpret_cast<const bf16x8*>(wqp + ot * 4096 + kn * 512);
                fk_n[ot] = *reinterpret_cast<const bf16x8*>(wkp + ot * 4096 + kn * 512);
            }
#pragma unroll
            for (int ot = 0; ot < 2; ++ot) {
                accq[ot] = MFMA16(a_c, fq_c[ot], accq[ot]);
                acck[ot] = MFMA16(a_c, fk_c[ot], acck[ot]);
            }
            a_c = a_n;
#pragma unroll
            for (int ot = 0; ot < 2; ++ot) { fq_c[ot] = fq_n[ot]; fk_c[ot] = fk_n[ot]; }
        }
        for (int ot = 0; ot < 2; ++ot) {
            const int o = 16 * ot + r;
            const float biq = bq[o];
            const float bik = bk[o];
            for (int i = 0; i < 4; ++i) {
                const int n = n0 + 16 * w + 4 * q + i;
                ft[((size_t)b * NN + n) * NC8 + o] = (bf16_t)(accq[ot][i] + biq);
                gt[((size_t)b * NN + n) * NC8 + o] = (bf16_t)(acck[ot][i] + bik);
            }
        }
    }

    // ---- v projection: wave w owns c-rows [64w,64w+64); all 64 n
    f32x4 vacc[4][4];
    for (int ct = 0; ct < 4; ++ct)
        for (int nt = 0; nt < 4; ++nt) vacc[ct][nt] = (f32x4){0.f, 0.f, 0.f, 0.f};

    const bf16_t* wvp  = wv + (size_t)w * 4096 + fo;               // + ct*16384 + kp*512
    const bf16_t* vpan = xpb + (size_t)(n0 >> 4) * 4096 + fo;      // + nt*4096 + kp*512

    bf16x8 wv_c[4], bfr_c[4];
#pragma unroll
    for (int ct = 0; ct < 4; ++ct)
        wv_c[ct] = *reinterpret_cast<const bf16x8*>(wvp + (size_t)ct * 16384);
#pragma unroll
    for (int nt = 0; nt < 4; ++nt)
        bfr_c[nt] = *reinterpret_cast<const bf16x8*>(vpan + (size_t)nt * 4096);

    for (int kp = 0; kp < 8; ++kp) {
        const int kn = (kp + 1 < 8) ? kp + 1 : 0;
        bf16x8 wv_n[4], bfr_n[4];
#pragma unroll
        for (int ct = 0; ct < 4; ++ct)
            wv_n[ct] = *reinterpret_cast<const bf16x8*>(wvp + (size_t)ct * 16384 + kn * 512);
#pragma unroll
        for (int nt = 0; nt < 4; ++nt)
            bfr_n[nt] = *reinterpret_cast<const bf16x8*>(vpan + (size_t)nt * 4096 + kn * 512);
#pragma unroll
        for (int ct = 0; ct < 4; ++ct)
#pragma unroll
            for (int nt = 0; nt < 4; ++nt)
                vacc[ct][nt] = MFMA16(wv_c[ct], bfr_c[nt], vacc[ct][nt]);
#pragma unroll
        for (int ct = 0; ct < 4; ++ct) wv_c[ct] = wv_n[ct];
#pragma unroll
        for (int nt = 0; nt < 4; ++nt) bfr_c[nt] = bfr_n[nt];
    }
    // ---- h epilogue: tiled layout h32[b][n/32][c][n%32]
    for (int ct = 0; ct < 4; ++ct) {
        for (int nt = 0; nt < 4; ++nt) {
            const int n32 = (n0 >> 5) + (nt >> 1);          // global n/32 chunk
            const int dn  = 16 * (nt & 1) + r;              // n%32
            for (int i = 0; i < 4; ++i) {
                const int c = 64 * ct + 16 * w + 4 * q + i;
                h[(((size_t)b * 128 + n32) * NC + c) * 32 + dn] = (bf16_t)(vacc[ct][nt][i] + bv[c]);
            }
        }
    }
}

// ---------------------------------------------------------------------------
// Kernel 2: attention (byte-identical to round 6: 90.8 us, MfmaUtil 36.5).
// ---------------------------------------------------------------------------
#define O_STEP(HU, HL, KC, LOFF)                                               \
    {                                                                          \
        _Pragma("unroll")                                                      \
        for (int ct = 0; ct < 2; ++ct)                                         \
            HL[ct] = *reinterpret_cast<const bf16x8*>(                         \
                hrow[ct] + (size_t)(LOFF) * 256);                              \
        bf16x8 pf[4];                                                          \
        _Pragma("unroll")                                                      \
        for (int mt = 0; mt < 4; ++mt) {                                       \
            const int row = 16 * mt + r;                                       \
            pf[mt] = *reinterpret_cast<const bf16x8*>(                         \
                &Pb[(row << 7) + (((4 * (KC) + q) ^ rq) << 3)]);               \
        }                                                                      \
        _Pragma("unroll")                                                      \
        for (int ct = 0; ct < 2; ++ct)                                         \
            _Pragma("unroll")                                                  \
            for (int mt = 0; mt < 4; ++mt)                                     \
                acc[ct][mt] = MFMA16(HU[ct], pf[mt], acc[ct][mt]);             \
    }

__global__ __launch_bounds__(512, 4) void attn(const bf16_t* __restrict__ ft,
                                               const bf16_t* __restrict__ gt,
                                               const bf16_t* __restrict__ h,
                                               float* __restrict__ out) {
    __shared__ bf16_t P[2 * 64 * 128];   // 32 KB, double buffered
    __shared__ float  l_lds[64];

    const int bx = blockIdx.x;       // 512
    const int b  = bx & 7;           // XCD pin
    const int m0 = (bx >> 3) * 64;
    const int tid  = threadIdx.x;
    const int w    = tid >> 6;       // 0..7
    const int lane = tid & 63;
    const int q    = lane >> 4;
    const int r    = lane & 15;
    const int rq   = r & 7;

    if (tid < 64) l_lds[tid] = 0.f;

    bf16x8 qf[4];
#pragma unroll
    for (int mt = 0; mt < 4; ++mt)
        qf[mt] = *reinterpret_cast<const bf16x8*>(
            gt + ((size_t)b * NN + m0 + 16 * mt + r) * NC8 + 8 * q);

    f32x4 acc[2][4];
#pragma unroll
    for (int ct = 0; ct < 2; ++ct)
#pragma unroll
        for (int mt = 0; mt < 4; ++mt) acc[ct][mt] = (f32x4){0.f, 0.f, 0.f, 0.f};
    float lp[4] = {0.f, 0.f, 0.f, 0.f};

    const bf16_t* fb = ft + (size_t)b * NN * NC8;
    const bf16_t* hb = h + (size_t)b * 128 * NC * 32;   // h32[b]...
    const f32x4 zero = (f32x4){0.f, 0.f, 0.f, 0.f};

    const bf16_t* hrow[2];
#pragma unroll
    for (int ct = 0; ct < 2; ++ct)
        hrow[ct] = hb + (size_t)(32 * w + 16 * ct + r) * 32 + 8 * q;
    const bf16_t* fptr = fb + (size_t)(16 * w + r) * NC8 + 8 * q;

    // ---- prologue: s(chunk 0); h0 = chunk0/kc0
    f32x4 s[4];
    {
        bf16x8 a0 = *reinterpret_cast<const bf16x8*>(fptr);
#pragma unroll
        for (int mt = 0; mt < 4; ++mt) s[mt] = MFMA16(a0, qf[mt], zero);
    }
    bf16x8 h0[2], h1[2];
#pragma unroll
    for (int ct = 0; ct < 2; ++ct)
        h0[ct] = *reinterpret_cast<const bf16x8*>(hrow[ct]);

    for (int ii = 0; ii < 32; ++ii) {
        bf16_t* Pb = &P[(ii & 1) << 13];
        const int nb = ii * 128;
        const int nld = (ii + 1 < 32 ? ii + 1 : 31) * 128;

        // ---- issue af load for chunk ii+1 FIRST (max slack, crosses barrier)
        bf16x8 af0 = *reinterpret_cast<const bf16x8*>(fptr + (size_t)nld * NC8);

        // ---- exp + write P[cur]
#pragma unroll
        for (int mt = 0; mt < 4; ++mt) {
            float e0 = __expf(s[mt][0]);
            float e1 = __expf(s[mt][1]);
            float e2 = __expf(s[mt][2]);
            float e3 = __expf(s[mt][3]);
            lp[mt] += (e0 + e1) + (e2 + e3);
            bf16x4 pv;
            pv[0] = (bf16_t)e0; pv[1] = (bf16_t)e1; pv[2] = (bf16_t)e2; pv[3] = (bf16_t)e3;
            const int row  = 16 * mt + r;
            const int nblk = 2 * w + (q >> 1);
            *reinterpret_cast<bf16x4*>(
                &Pb[(row << 7) + ((nblk ^ rq) << 3) + 4 * (q & 1)]) = pv;
        }

        // ---- NON-DRAINING barrier: order LDS only; VMEM prefetch survives
        asm volatile("s_waitcnt lgkmcnt(0)" ::: "memory");
        __builtin_amdgcn_sched_barrier(0);
        __builtin_amdgcn_s_barrier();
        __builtin_amdgcn_sched_barrier(0);

        // ---- O phase: 4 k-chunks of 32 n, h ping-pong one chunk ahead
        const int nbn = (ii + 1 < 32 ? nb + 128 : nb);
        __builtin_amdgcn_s_setprio(1);
        O_STEP(h0, h1, 0, nb + 32);
        O_STEP(h1, h0, 1, nb + 64);
        O_STEP(h0, h1, 2, nb + 96);
        O_STEP(h1, h0, 3, nbn);

        // ---- S(ii+1)
#pragma unroll
        for (int mt = 0; mt < 4; ++mt) s[mt] = MFMA16(af0, qf[mt], zero);
        __builtin_amdgcn_s_setprio(0);
    }

    // ---- reduce l partials
    __syncthreads();
#pragma unroll
    for (int mt = 0; mt < 4; ++mt) {
        float v = lp[mt];
        v += __shfl_xor(v, 16);
        v += __shfl_xor(v, 32);
        if (q == 0) atomicAdd(&l_lds[16 * mt + r], v);
    }
    __syncthreads();

    // ---- epilogue: out[b][c][m] = acc / l[m]
#pragma unroll
    for (int ct = 0; ct < 2; ++ct) {
#pragma unroll
        for (int mt = 0; mt < 4; ++mt) {
            const int m = m0 + 16 * mt + r;
            const float linv = 1.0f / l_lds[16 * mt + r];
#pragma unroll
            for (int i = 0; i < 4; ++i) {
                const int c = 32 * w + 16 * ct + 4 * q + i;
                out[((size_t)b * NC + c) * NN + m] = acc[ct][mt][i] * linv;
            }
        }
    }
}

extern "C" void kernel_launch(void* const* d_in, const int* in_sizes, int n_in,
                              void* d_out, int out_size, void* d_ws, size_t ws_size,
                              hipStream_t stream) {
    const float* x  = (const float*)d_in[0];
    const float* wq = (const float*)d_in[1];
    const float* bq = (const float*)d_in[2];
    const float* wk = (const float*)d_in[3];
    const float* bk = (const float*)d_in[4];
    const float* wv = (const float*)d_in[5];
    const float* bv = (const float*)d_in[6];
    float* out = (float*)d_out;

    bf16_t* ft  = (bf16_t*)d_ws;                     // [B][N][32]
    bf16_t* gt  = ft + (size_t)NB * NN * NC8;        // [B][N][32]
    bf16_t* hb  = gt + (size_t)NB * NN * NC8;        // h32: [B][N/32][C][32]
    bf16_t* wqb = hb + (size_t)NB * NC * NN;         // 16 panels
    bf16_t* wkb = wqb + (size_t)NC8 * NC;            // 16 panels
    bf16_t* wvb = wkb + (size_t)NC8 * NC;            // 128 panels

    // xP scratch lives in d_out (16.8 MB of 33.5 MB); attn overwrites out
    // completely afterwards (stream-ordered), so no conflict.
    bf16_t* xT = (bf16_t*)out;                       // panels [B][256][8][512]

    cvt_all<<<80, 256, 0, stream>>>(wq, wk, wv, wqb, wkb, wvb);
    xpose<<<NB * (NN / 64), 256, 0, stream>>>(x, xT);
    projmm<<<NB * (NN / 64), 256, 0, stream>>>(xT, wqb, bq, wkb, bk, wvb, bv, ft, gt, hb);
    attn<<<NB * (NN / 64), 512, 0, stream>>>(ft, gt, hb, out);
}

// Round 9
// 188.130 us; speedup vs baseline: 1.0794x; 1.0421x over previous
//
#include <hip/hip_runtime.h>
#include <hip/hip_bf16.h>

typedef __bf16 bf16_t;
typedef __bf16 bf16x8 __attribute__((ext_vector_type(8)));
typedef __bf16 bf16x4 __attribute__((ext_vector_type(4)));
typedef float  f32x4  __attribute__((ext_vector_type(4)));

#define NB  8
#define NC  256
#define NC8 32
#define NN  4096
#define XS  264   // xs row stride (528B = 33*16, b128-aligned)

#define MFMA16(a, b, c) __builtin_amdgcn_mfma_f32_16x16x32_bf16((a), (b), (c), 0, 0, 0)

// ---------------------------------------------------------------------------
// Weight panel layout: mat[R][256] -> element (o,k) at
//   panel[(o/16)*8 + k/32]*512 + (o&15)*32 + (k&31)
// Fragment load per wave (r*32 + 8q within panel) = contiguous 1KB.
// ---------------------------------------------------------------------------

// ---------------------------------------------------------------------------
// Kernel 0: fp32 -> bf16 + panelize all three weight matrices.
// ---------------------------------------------------------------------------
__global__ __launch_bounds__(256) void cvt_all(const float* __restrict__ wq,
                                               const float* __restrict__ wk,
                                               const float* __restrict__ wv,
                                               bf16_t* __restrict__ wqb,
                                               bf16_t* __restrict__ wkb,
                                               bf16_t* __restrict__ wvb) {
    int i = blockIdx.x * 256 + threadIdx.x;   // 0..20479
    const float* src; bf16_t* dst; int off;
    if (i < 2048)      { src = wq; dst = wqb; off = i; }
    else if (i < 4096) { src = wk; dst = wkb; off = i - 2048; }
    else               { src = wv; dst = wvb; off = i - 4096; }
    float4 v = reinterpret_cast<const float4*>(src)[off];
    const int e = off * 4;        // element offset in row-major [R][256]
    const int o = e >> 8;         // row
    const int k = e & 255;        // col (multiple of 4 -> one panel)
    const size_t d = (size_t)((o >> 4) * 8 + (k >> 5)) * 512 + (o & 15) * 32 + (k & 31);
    bf16x4 ov;
    ov[0] = (bf16_t)v.x; ov[1] = (bf16_t)v.y; ov[2] = (bf16_t)v.z; ov[3] = (bf16_t)v.w;
    *reinterpret_cast<bf16x4*>(dst + d) = ov;
}

// ---------------------------------------------------------------------------
// Kernel 1: FUSED transpose + q/k/v projections (no xP HBM roundtrip).
//   - x loads hoisted (16 float4 in flight), two-phase LDS transpose -> xs.
//   - kp=0 weight fragments prefetched BEFORE the transpose (latency hidden).
//   - MFMA operand order SWAPPED vs earlier rounds so every epilogue store is
//     a bf16x4: MFMA16(W, act) puts the o/c axis on 4q+i (stored-contiguous),
//     the n axis on r.  h: 64 scalar stores/thread -> 16 x 8B; ft/gt: 16 -> 4.
//   - Weights panelized (contiguous 1KB fragment loads), depth-1 prefetch.
// ---------------------------------------------------------------------------
__global__ __launch_bounds__(256) void proj2(const float* __restrict__ x,
                                             const bf16_t* __restrict__ wq,
                                             const float* __restrict__ bq,
                                             const bf16_t* __restrict__ wk,
                                             const float* __restrict__ bk,
                                             const bf16_t* __restrict__ wv,
                                             const float* __restrict__ bv,
                                             bf16_t* __restrict__ ft,
                                             bf16_t* __restrict__ gt,
                                             bf16_t* __restrict__ h) {
    __shared__ bf16_t tile[64][72];
    __shared__ bf16_t xs[64 * XS];      // [n_loc][c]

    const int bx = blockIdx.x;          // 512
    const int b  = bx >> 6;
    const int n0 = (bx & 63) * 64;
    const int t  = threadIdx.x;
    const int w    = t >> 6;
    const int lane = t & 63;
    const int q    = lane >> 4;
    const int r    = lane & 15;

    const int cl  = t >> 4;
    const int nl  = (t & 15) * 4;
    const int nb_ = t >> 3;
    const int cl2 = (t & 7) * 8;

    // ---- hoisted x loads: all 16 in flight at once
    float4 xv[16];
#pragma unroll
    for (int cp = 0; cp < 4; ++cp)
#pragma unroll
        for (int p = 0; p < 4; ++p)
            xv[4 * cp + p] = *reinterpret_cast<const float4*>(
                x + ((size_t)b * NC + 64 * cp + cl + 16 * p) * NN + n0 + nl);

    // ---- early weight prefetch (kp=0 fragments) — hides under transpose
    const int fo = r * 32 + 8 * q;      // within-panel fragment offset
    bf16x8 fq_c[2], fk_c[2], wv_c[4];
#pragma unroll
    for (int ot = 0; ot < 2; ++ot) {
        fq_c[ot] = *reinterpret_cast<const bf16x8*>(wq + ot * 4096 + fo);
        fk_c[ot] = *reinterpret_cast<const bf16x8*>(wk + ot * 4096 + fo);
    }
#pragma unroll
    for (int ct = 0; ct < 4; ++ct)
        wv_c[ct] = *reinterpret_cast<const bf16x8*>(
            wv + (size_t)w * 4096 + (size_t)ct * 16384 + fo);

    // ---- two-phase LDS transpose (proven)
    for (int cp = 0; cp < 4; ++cp) {
#pragma unroll
        for (int p = 0; p < 4; ++p) {
            const int cc = cl + 16 * p;
            float4 v = xv[4 * cp + p];
            bf16x4 bv4;
            bv4[0] = (bf16_t)v.x; bv4[1] = (bf16_t)v.y; bv4[2] = (bf16_t)v.z; bv4[3] = (bf16_t)v.w;
            *reinterpret_cast<bf16x4*>(&tile[cc][nl]) = bv4;
        }
        __syncthreads();
#pragma unroll
        for (int p = 0; p < 2; ++p) {
            const int nn = nb_ + 32 * p;
            bf16x8 v;
            for (int i = 0; i < 8; ++i) v[i] = tile[cl2 + i][nn];
            *reinterpret_cast<bf16x8*>(&xs[nn * XS + 64 * cp + cl2]) = v;
        }
        __syncthreads();
    }

    // ---- q/k projections: wave w owns n-rows [16w,16w+16); n on r-axis
    {
        const bf16_t* xrow = &xs[(16 * w + r) * XS];
        f32x4 accq[2], acck[2];
        for (int ot = 0; ot < 2; ++ot) {
            accq[ot] = (f32x4){0.f, 0.f, 0.f, 0.f};
            acck[ot] = (f32x4){0.f, 0.f, 0.f, 0.f};
        }
        bf16x8 a_c = *reinterpret_cast<const bf16x8*>(xrow + 8 * q);
        for (int kp = 0; kp < 8; ++kp) {
            const int kn = (kp + 1 < 8) ? kp + 1 : 0;
            bf16x8 a_n = *reinterpret_cast<const bf16x8*>(xrow + kn * 32 + 8 * q);
            bf16x8 fq_n[2], fk_n[2];
#pragma unroll
            for (int ot = 0; ot < 2; ++ot) {
                fq_n[ot] = *reinterpret_cast<const bf16x8*>(wq + ot * 4096 + kn * 512 + fo);
                fk_n[ot] = *reinterpret_cast<const bf16x8*>(wk + ot * 4096 + kn * 512 + fo);
            }
#pragma unroll
            for (int ot = 0; ot < 2; ++ot) {
                accq[ot] = MFMA16(fq_c[ot], a_c, accq[ot]);   // o on 4q+i, n on r
                acck[ot] = MFMA16(fk_c[ot], a_c, acck[ot]);
            }
            a_c = a_n;
#pragma unroll
            for (int ot = 0; ot < 2; ++ot) { fq_c[ot] = fq_n[ot]; fk_c[ot] = fk_n[ot]; }
        }
        const int n = n0 + 16 * w + r;
#pragma unroll
        for (int ot = 0; ot < 2; ++ot) {
            const int o4 = 16 * ot + 4 * q;
            float4 b4q = *reinterpret_cast<const float4*>(bq + o4);
            float4 b4k = *reinterpret_cast<const float4*>(bk + o4);
            bf16x4 pq, pk;
            pq[0] = (bf16_t)(accq[ot][0] + b4q.x); pq[1] = (bf16_t)(accq[ot][1] + b4q.y);
            pq[2] = (bf16_t)(accq[ot][2] + b4q.z); pq[3] = (bf16_t)(accq[ot][3] + b4q.w);
            pk[0] = (bf16_t)(acck[ot][0] + b4k.x); pk[1] = (bf16_t)(acck[ot][1] + b4k.y);
            pk[2] = (bf16_t)(acck[ot][2] + b4k.z); pk[3] = (bf16_t)(acck[ot][3] + b4k.w);
            *reinterpret_cast<bf16x4*>(ft + ((size_t)b * NN + n) * NC8 + o4) = pq;
            *reinterpret_cast<bf16x4*>(gt + ((size_t)b * NN + n) * NC8 + o4) = pk;
        }
    }

    // ---- v projection: c = 64ct+16w+r (B-side), n = 16nt+4q+i (A-side)
    f32x4 vacc[4][4];
    for (int ct = 0; ct < 4; ++ct)
        for (int nt = 0; nt < 4; ++nt) vacc[ct][nt] = (f32x4){0.f, 0.f, 0.f, 0.f};

    bf16x8 bfr_c[4];
#pragma unroll
    for (int nt = 0; nt < 4; ++nt)
        bfr_c[nt] = *reinterpret_cast<const bf16x8*>(&xs[(16 * nt + r) * XS + 8 * q]);

    for (int kp = 0; kp < 8; ++kp) {
        const int kn = (kp + 1 < 8) ? kp + 1 : 0;
        bf16x8 wv_n[4], bfr_n[4];
#pragma unroll
        for (int ct = 0; ct < 4; ++ct)
            wv_n[ct] = *reinterpret_cast<const bf16x8*>(
                wv + (size_t)w * 4096 + (size_t)ct * 16384 + kn * 512 + fo);
#pragma unroll
        for (int nt = 0; nt < 4; ++nt)
            bfr_n[nt] = *reinterpret_cast<const bf16x8*>(&xs[(16 * nt + r) * XS + kn * 32 + 8 * q]);
#pragma unroll
        for (int ct = 0; ct < 4; ++ct)
#pragma unroll
            for (int nt = 0; nt < 4; ++nt)
                vacc[ct][nt] = MFMA16(bfr_c[nt], wv_c[ct], vacc[ct][nt]);
#pragma unroll
        for (int ct = 0; ct < 4; ++ct) wv_c[ct] = wv_n[ct];
#pragma unroll
        for (int nt = 0; nt < 4; ++nt) bfr_c[nt] = bfr_n[nt];
    }

    // ---- h epilogue: h32[b][n/32][c][n%32], bf16x4 stores (n contig per thread)
#pragma unroll
    for (int ct = 0; ct < 4; ++ct) {
        const int c = 64 * ct + 16 * w + r;
        const float bvc = bv[c];
#pragma unroll
        for (int nt = 0; nt < 4; ++nt) {
            const int n32 = (n0 >> 5) + (nt >> 1);
            const int dn0 = 16 * (nt & 1) + 4 * q;
            bf16x4 pv;
            pv[0] = (bf16_t)(vacc[ct][nt][0] + bvc);
            pv[1] = (bf16_t)(vacc[ct][nt][1] + bvc);
            pv[2] = (bf16_t)(vacc[ct][nt][2] + bvc);
            pv[3] = (bf16_t)(vacc[ct][nt][3] + bvc);
            *reinterpret_cast<bf16x4*>(
                h + (((size_t)b * 128 + n32) * NC + c) * 32 + dn0) = pv;
        }
    }
}

// ---------------------------------------------------------------------------
// Kernel 2: attention (byte-identical to round 6: 90.8 us, MfmaUtil 36.5).
// ---------------------------------------------------------------------------
#define O_STEP(HU, HL, KC, LOFF)                                               \
    {                                                                          \
        _Pragma("unroll")                                                      \
        for (int ct = 0; ct < 2; ++ct)                                         \
            HL[ct] = *reinterpret_cast<const bf16x8*>(                         \
                hrow[ct] + (size_t)(LOFF) * 256);                              \
        bf16x8 pf[4];                                                          \
        _Pragma("unroll")                                                      \
        for (int mt = 0; mt < 4; ++mt) {                                       \
            const int row = 16 * mt + r;                                       \
            pf[mt] = *reinterpret_cast<const bf16x8*>(                         \
                &Pb[(row << 7) + (((4 * (KC) + q) ^ rq) << 3)]);               \
        }                                                                      \
        _Pragma("unroll")                                                      \
        for (int ct = 0; ct < 2; ++ct)                                         \
            _Pragma("unroll")                                                  \
            for (int mt = 0; mt < 4; ++mt)                                     \
                acc[ct][mt] = MFMA16(HU[ct], pf[mt], acc[ct][mt]);             \
    }

__global__ __launch_bounds__(512, 4) void attn(const bf16_t* __restrict__ ft,
                                               const bf16_t* __restrict__ gt,
                                               const bf16_t* __restrict__ h,
                                               float* __restrict__ out) {
    __shared__ bf16_t P[2 * 64 * 128];   // 32 KB, double buffered
    __shared__ float  l_lds[64];

    const int bx = blockIdx.x;       // 512
    const int b  = bx & 7;           // XCD pin
    const int m0 = (bx >> 3) * 64;
    const int tid  = threadIdx.x;
    const int w    = tid >> 6;       // 0..7
    const int lane = tid & 63;
    const int q    = lane >> 4;
    const int r    = lane & 15;
    const int rq   = r & 7;

    if (tid < 64) l_lds[tid] = 0.f;

    bf16x8 qf[4];
#pragma unroll
    for (int mt = 0; mt < 4; ++mt)
        qf[mt] = *reinterpret_cast<const bf16x8*>(
            gt + ((size_t)b * NN + m0 + 16 * mt + r) * NC8 + 8 * q);

    f32x4 acc[2][4];
#pragma unroll
    for (int ct = 0; ct < 2; ++ct)
#pragma unroll
        for (int mt = 0; mt < 4; ++mt) acc[ct][mt] = (f32x4){0.f, 0.f, 0.f, 0.f};
    float lp[4] = {0.f, 0.f, 0.f, 0.f};

    const bf16_t* fb = ft + (size_t)b * NN * NC8;
    const bf16_t* hb = h + (size_t)b * 128 * NC * 32;   // h32[b]...
    const f32x4 zero = (f32x4){0.f, 0.f, 0.f, 0.f};

    const bf16_t* hrow[2];
#pragma unroll
    for (int ct = 0; ct < 2; ++ct)
        hrow[ct] = hb + (size_t)(32 * w + 16 * ct + r) * 32 + 8 * q;
    const bf16_t* fptr = fb + (size_t)(16 * w + r) * NC8 + 8 * q;

    // ---- prologue: s(chunk 0); h0 = chunk0/kc0
    f32x4 s[4];
    {
        bf16x8 a0 = *reinterpret_cast<const bf16x8*>(fptr);
#pragma unroll
        for (int mt = 0; mt < 4; ++mt) s[mt] = MFMA16(a0, qf[mt], zero);
    }
    bf16x8 h0[2], h1[2];
#pragma unroll
    for (int ct = 0; ct < 2; ++ct)
        h0[ct] = *reinterpret_cast<const bf16x8*>(hrow[ct]);

    for (int ii = 0; ii < 32; ++ii) {
        bf16_t* Pb = &P[(ii & 1) << 13];
        const int nb = ii * 128;
        const int nld = (ii + 1 < 32 ? ii + 1 : 31) * 128;

        // ---- issue af load for chunk ii+1 FIRST (max slack, crosses barrier)
        bf16x8 af0 = *reinterpret_cast<const bf16x8*>(fptr + (size_t)nld * NC8);

        // ---- exp + write P[cur]
#pragma unroll
        for (int mt = 0; mt < 4; ++mt) {
            float e0 = __expf(s[mt][0]);
            float e1 = __expf(s[mt][1]);
            float e2 = __expf(s[mt][2]);
            float e3 = __expf(s[mt][3]);
            lp[mt] += (e0 + e1) + (e2 + e3);
            bf16x4 pv;
            pv[0] = (bf16_t)e0; pv[1] = (bf16_t)e1; pv[2] = (bf16_t)e2; pv[3] = (bf16_t)e3;
            const int row  = 16 * mt + r;
            const int nblk = 2 * w + (q >> 1);
            *reinterpret_cast<bf16x4*>(
                &Pb[(row << 7) + ((nblk ^ rq) << 3) + 4 * (q & 1)]) = pv;
        }

        // ---- NON-DRAINING barrier: order LDS only; VMEM prefetch survives
        asm volatile("s_waitcnt lgkmcnt(0)" ::: "memory");
        __builtin_amdgcn_sched_barrier(0);
        __builtin_amdgcn_s_barrier();
        __builtin_amdgcn_sched_barrier(0);

        // ---- O phase: 4 k-chunks of 32 n, h ping-pong one chunk ahead
        const int nbn = (ii + 1 < 32 ? nb + 128 : nb);
        __builtin_amdgcn_s_setprio(1);
        O_STEP(h0, h1, 0, nb + 32);
        O_STEP(h1, h0, 1, nb + 64);
        O_STEP(h0, h1, 2, nb + 96);
        O_STEP(h1, h0, 3, nbn);

        // ---- S(ii+1)
#pragma unroll
        for (int mt = 0; mt < 4; ++mt) s[mt] = MFMA16(af0, qf[mt], zero);
        __builtin_amdgcn_s_setprio(0);
    }

    // ---- reduce l partials
    __syncthreads();
#pragma unroll
    for (int mt = 0; mt < 4; ++mt) {
        float v = lp[mt];
        v += __shfl_xor(v, 16);
        v += __shfl_xor(v, 32);
        if (q == 0) atomicAdd(&l_lds[16 * mt + r], v);
    }
    __syncthreads();

    // ---- epilogue: out[b][c][m] = acc / l[m]
#pragma unroll
    for (int ct = 0; ct < 2; ++ct) {
#pragma unroll
        for (int mt = 0; mt < 4; ++mt) {
            const int m = m0 + 16 * mt + r;
            const float linv = 1.0f / l_lds[16 * mt + r];
#pragma unroll
            for (int i = 0; i < 4; ++i) {
                const int c = 32 * w + 16 * ct + 4 * q + i;
                out[((size_t)b * NC + c) * NN + m] = acc[ct][mt][i] * linv;
            }
        }
    }
}

extern "C" void kernel_launch(void* const* d_in, const int* in_sizes, int n_in,
                              void* d_out, int out_size, void* d_ws, size_t ws_size,
                              hipStream_t stream) {
    const float* x  = (const float*)d_in[0];
    const float* wq = (const float*)d_in[1];
    const float* bq = (const float*)d_in[2];
    const float* wk = (const float*)d_in[3];
    const float* bk = (const float*)d_in[4];
    const float* wv = (const float*)d_in[5];
    const float* bv = (const float*)d_in[6];
    float* out = (float*)d_out;

    bf16_t* ft  = (bf16_t*)d_ws;                     // [B][N][32]
    bf16_t* gt  = ft + (size_t)NB * NN * NC8;        // [B][N][32]
    bf16_t* hb  = gt + (size_t)NB * NN * NC8;        // h32: [B][N/32][C][32]
    bf16_t* wqb = hb + (size_t)NB * NC * NN;         // 16 panels
    bf16_t* wkb = wqb + (size_t)NC8 * NC;            // 16 panels
    bf16_t* wvb = wkb + (size_t)NC8 * NC;            // 128 panels

    cvt_all<<<80, 256, 0, stream>>>(wq, wk, wv, wqb, wkb, wvb);
    proj2<<<NB * (NN / 64), 256, 0, stream>>>(x, wqb, bq, wkb, bk, wvb, bv, ft, gt, hb);
    attn<<<NB * (NN / 64), 512, 0, stream>>>(ft, gt, hb, out);
}